// Round 2
// baseline (2301.390 us; speedup 1.0000x reference)
//
#include <hip/hip_runtime.h>
#include <hip/hip_bf16.h>
#include <stdint.h>

// MoE gate: T=524288, D=256, E=64, groups=2x32, topk=4.
// 1-wave blocks (64 threads), each computes 64 rows x 64 experts, self-paced
// double-buffered global_load_lds pipeline (no __syncthreads anywhere),
// fully in-register softmax/top-4 epilogue via __shfl_xor.

#define NCH 32  // 256 d / 8 per chunk

__device__ __forceinline__ void gload16(const void* g, void* l) {
  __builtin_amdgcn_global_load_lds(
      (const __attribute__((address_space(1))) void*)g,
      (__attribute__((address_space(3))) void*)l, 16, 0, 0);
}

__global__ __launch_bounds__(64, 4) void gate_kernel(
    const float* __restrict__ x, const float* __restrict__ W,
    float* __restrict__ out, int T) {
  // Double buffers as DISTINCT objects so alias analysis permits counted
  // vmcnt waits (no conservative full drain).
  __shared__ float XS0[512], XS1[512], WS0[512], WS1[512];  // 8 KB total

  const int lane = threadIdx.x;      // 0..63
  const int li = lane & 7;           // row sub-index
  const int lj = lane >> 3;          // expert octet
  const int base_row = blockIdx.x * 64;

  float acc[8][8];
#pragma unroll
  for (int a = 0; a < 8; ++a)
#pragma unroll
    for (int b = 0; b < 8; ++b) acc[a][b] = 0.f;

  // ---- staging constants (per-lane) ----
  // x tile: 64 rows x 8 floats = 128 16B slots, LINEAR (reads are 2-way free).
  // W tile: 64 experts x 8 floats, XOR-swizzled per expert-octet so reads
  // spread across banks; swizzle applied on the GLOBAL source (linear LDS
  // dest is required by global_load_lds).
  const int L0 = lane, L1 = lane + 64;
  const int S0w = L0 ^ ((L0 >> 4) & 7);
  const int S1w = L1 ^ ((L1 >> 4) & 7);
  const float* xsrc0 = x + (size_t)(base_row + (L0 >> 1)) * 256 + (L0 & 1) * 4;
  const float* xsrc1 = x + (size_t)(base_row + (L1 >> 1)) * 256 + (L1 & 1) * 4;
  const float* wsrc0 = W + (size_t)(S0w >> 1) * 256 + (S0w & 1) * 4;
  const float* wsrc1 = W + (size_t)(S1w >> 1) * 256 + (S1w & 1) * 4;

  auto stage = [&](float* XD, float* WD, int c) {
    gload16(xsrc0 + c * 8, XD + L0 * 4);
    gload16(xsrc1 + c * 8, XD + L1 * 4);
    gload16(wsrc0 + c * 8, WD + L0 * 4);
    gload16(wsrc1 + c * 8, WD + L1 * 4);
  };

  auto compute = [&](const float* XB, const float* WB) {
#pragma unroll
    for (int dc = 0; dc < 2; ++dc) {
      float4 wv[8];
#pragma unroll
      for (int b = 0; b < 8; ++b)
        wv[b] = *(const float4*)&WB[(16 * lj + ((2 * b + dc) ^ lj)) << 2];
#pragma unroll
      for (int a = 0; a < 8; ++a) {
        float4 xv = *(const float4*)&XB[(16 * a + 2 * li + dc) << 2];
#pragma unroll
        for (int b = 0; b < 8; ++b) {
          acc[a][b] = fmaf(xv.x, wv[b].x, acc[a][b]);
          acc[a][b] = fmaf(xv.y, wv[b].y, acc[a][b]);
          acc[a][b] = fmaf(xv.z, wv[b].z, acc[a][b]);
          acc[a][b] = fmaf(xv.w, wv[b].w, acc[a][b]);
        }
      }
    }
  };

  stage(XS0, WS0, 0);
#pragma unroll 1
  for (int c = 0; c < NCH; c += 2) {
    if (c + 1 < NCH) stage(XS1, WS1, c + 1);
    compute(XS0, WS0);
    if (c + 2 < NCH) stage(XS0, WS0, c + 2);
    compute(XS1, WS1);
  }

  // ---- in-register epilogue ----
  // Lanes {li, li+8, ..., li+56} (xor masks 8/16/32) share row 8a+li and
  // together hold all 64 experts (lane lj owns experts 8lj..8lj+7).
  const float NEG = -__builtin_inff();
  float rw0 = 0, rw1 = 0, rw2 = 0, rw3 = 0;
  float ri0 = 0, ri1 = 0, ri2 = 0, ri3 = 0;

#pragma unroll
  for (int a = 0; a < 8; ++a) {
    // full-row max (for softmax shift)
    float m = acc[a][0];
#pragma unroll
    for (int b = 1; b < 8; ++b) m = fmaxf(m, acc[a][b]);
    m = fmaxf(m, __shfl_xor(m, 8));
    m = fmaxf(m, __shfl_xor(m, 16));
    m = fmaxf(m, __shfl_xor(m, 32));

    // probs + denom over all 64 experts
    float p[8];
    float ps = 0.f;
#pragma unroll
    for (int b = 0; b < 8; ++b) {
      p[b] = __expf(acc[a][b] - m);
      ps += p[b];
    }
    ps += __shfl_xor(ps, 8);
    ps += __shfl_xor(ps, 16);
    ps += __shfl_xor(ps, 32);
    float inv = 1.0f / ps;

    // group selection on PROBS (matches reference: scores-domain, tie->g0)
    float gm = p[0];
#pragma unroll
    for (int b = 1; b < 8; ++b) gm = fmaxf(gm, p[b]);
    gm = fmaxf(gm, __shfl_xor(gm, 8));
    gm = fmaxf(gm, __shfl_xor(gm, 16));  // own-group (lj quad) max
    float go = __shfl_xor(gm, 32);       // other group's max
    float pm0 = (lj < 4) ? gm : go;
    float pm1 = (lj < 4) ? go : gm;
    int g = (pm1 > pm0) ? 1 : 0;
    bool sel = ((lj >> 2) == g);

    float cand[8];
#pragma unroll
    for (int b = 0; b < 8; ++b) cand[b] = sel ? p[b] : NEG;

    float w4[4];
    int e4[4];
#pragma unroll
    for (int it = 0; it < 4; ++it) {
      // local argmax (ascending strict > keeps lowest index on ties)
      float bv = cand[0];
      int bl = 0;
#pragma unroll
      for (int b = 1; b < 8; ++b) {
        bool cgt = cand[b] > bv;
        bv = cgt ? cand[b] : bv;
        bl = cgt ? b : bl;
      }
      int be = lj * 8 + bl;
      // butterfly argmax across the 8-lane expert group, lower-index ties
#pragma unroll
      for (int s = 0; s < 3; ++s) {
        int mask = 8 << s;
        float ov = __shfl_xor(bv, mask);
        int oe = __shfl_xor(be, mask);
        bool tk = (ov > bv) || (ov == bv && oe < be);
        bv = tk ? ov : bv;
        be = tk ? oe : be;
      }
      w4[it] = bv * inv;
      e4[it] = be;
      // mask out the winner (static indices only)
#pragma unroll
      for (int b = 0; b < 8; ++b)
        cand[b] = (lj * 8 + b == be) ? NEG : cand[b];
    }

    // lane (li,lj) keeps results of row-block a == lj -> row 8lj+li == lane
    bool keep = (lj == a);
    rw0 = keep ? w4[0] : rw0;
    rw1 = keep ? w4[1] : rw1;
    rw2 = keep ? w4[2] : rw2;
    rw3 = keep ? w4[3] : rw3;
    ri0 = keep ? (float)e4[0] : ri0;
    ri1 = keep ? (float)e4[1] : ri1;
    ri2 = keep ? (float)e4[2] : ri2;
    ri3 = keep ? (float)e4[3] : ri3;
  }

  size_t row = (size_t)base_row + lane;
  *(float4*)&out[row * 4] = make_float4(rw0, rw1, rw2, rw3);
  *(float4*)&out[(size_t)T * 4 + row * 4] =
      make_float4(ri0, ri1, ri2, ri3);
}

extern "C" void kernel_launch(void* const* d_in, const int* in_sizes, int n_in,
                              void* d_out, int out_size, void* d_ws,
                              size_t ws_size, hipStream_t stream) {
  const float* x = (const float*)d_in[0];
  const float* W = (const float*)d_in[1];
  float* out = (float*)d_out;
  int T = in_sizes[0] / 256;      // D = 256
  int grid = T / 64;              // 8192 one-wave blocks
  hipLaunchKernelGGL(gate_kernel, dim3(grid), dim3(64), 0, stream, x, W, out,
                     T);
}

// Round 4
// 309.680 us; speedup vs baseline: 7.4315x; 7.4315x over previous
//
#include <hip/hip_runtime.h>
#include <hip/hip_bf16.h>
#include <stdint.h>

// MoE gate: T=524288, D=256, E=64, groups=2x32, topk=4.
// Pass 1: logits^T = W @ x^T via mfma_f32_16x16x32_bf16 with exact 3-way
//   bf16 truncation split (6 cross terms). Selection in LOGIT domain.
//   Tokens whose selection margin < DELTA are appended to a fix-list in ws.
// Pass 2: flagged tokens recomputed with round-1-exact arithmetic
//   (single-accumulator ascending-d fmaf == np/BLAS order) and identical
//   selection semantics; overwrites their outputs. ~0.5% of tokens.

typedef __attribute__((ext_vector_type(8))) short bf16x8;
typedef __attribute__((ext_vector_type(4))) float f32x4;
typedef __attribute__((ext_vector_type(4))) int i32x4;

#define SPLIT_OFF 1024
#define LIST_OFF 102400
#define DELTA 5e-5f

__device__ __forceinline__ f32x4 mf(const i32x4& a, const i32x4& b,
                                    const f32x4& c) {
  return __builtin_amdgcn_mfma_f32_16x16x32_bf16(
      __builtin_bit_cast(bf16x8, a), __builtin_bit_cast(bf16x8, b), c, 0, 0, 0);
}

// low short = hi16(e0), high short = hi16(e1)
__device__ __forceinline__ int packhi(unsigned e0, unsigned e1) {
  return (int)__builtin_amdgcn_perm(e1, e0, 0x07060302u);
}

__global__ void zero_meta(int* meta) { meta[0] = 0; }

// exact truncation split of W into 3 bf16 levels (h+m+l == w bitwise)
__global__ void split_w(const float* __restrict__ W,
                        unsigned short* __restrict__ ws, int n) {
  int i = blockIdx.x * 256 + threadIdx.x;
  if (i >= n) return;
  float w = W[i];
  unsigned u = __float_as_uint(w);
  unsigned uh = u & 0xFFFF0000u;
  float rf = w - __uint_as_float(uh);
  unsigned um = __float_as_uint(rf) & 0xFFFF0000u;
  float lf = rf - __uint_as_float(um);
  ws[i] = (unsigned short)(uh >> 16);
  ws[n + i] = (unsigned short)(um >> 16);
  ws[2 * n + i] = (unsigned short)(__float_as_uint(lf) >> 16);
}

struct XFrags { i32x4 h, m, l; };

__device__ __forceinline__ XFrags split_x(const float4& q0, const float4& q1) {
  float xs[8] = {q0.x, q0.y, q0.z, q0.w, q1.x, q1.y, q1.z, q1.w};
  unsigned hu[8], mu[8], lu[8];
#pragma unroll
  for (int j = 0; j < 8; ++j) {
    unsigned u = __float_as_uint(xs[j]);
    unsigned uh = u & 0xFFFF0000u;
    float r = xs[j] - __uint_as_float(uh);
    unsigned um = __float_as_uint(r) & 0xFFFF0000u;
    float lf = r - __uint_as_float(um);
    hu[j] = u;
    mu[j] = __float_as_uint(r);
    lu[j] = __float_as_uint(lf);
  }
  XFrags f;
#pragma unroll
  for (int wd = 0; wd < 4; ++wd) {
    f.h[wd] = packhi(hu[2 * wd], hu[2 * wd + 1]);
    f.m[wd] = packhi(mu[2 * wd], mu[2 * wd + 1]);
    f.l[wd] = packhi(lu[2 * wd], lu[2 * wd + 1]);
  }
  return f;
}

__global__ __launch_bounds__(256, 2) void gate_kernel(
    const float* __restrict__ x, const unsigned short* __restrict__ wsp,
    float* __restrict__ out, int* __restrict__ meta, int* __restrict__ list,
    int cap, int T) {
  const int t = threadIdx.x;
  const int lane = t & 63;
  const int wid = t >> 6;
  const int le = lane & 15;
  const int lg = lane >> 4;
  const int tokbase = blockIdx.x * 128 + wid * 32;

  f32x4 acc[4][2];
#pragma unroll
  for (int nt = 0; nt < 4; ++nt)
#pragma unroll
    for (int tt = 0; tt < 2; ++tt) acc[nt][tt] = (f32x4)0.0f;

  const float* xr0 = x + (size_t)(tokbase + le) * 256 + lg * 8;
  const float* xr1 = xr0 + 16 * 256;
  const unsigned short* wb = wsp + (size_t)le * 256 + lg * 8;

  float4 xraw[3][2][2];
#pragma unroll
  for (int ps = 0; ps < 2; ++ps) {
    xraw[ps][0][0] = *(const float4*)(xr0 + ps * 32);
    xraw[ps][0][1] = *(const float4*)(xr0 + ps * 32 + 4);
    xraw[ps][1][0] = *(const float4*)(xr1 + ps * 32);
    xraw[ps][1][1] = *(const float4*)(xr1 + ps * 32 + 4);
  }

#pragma unroll
  for (int s = 0; s < 8; ++s) {
    if (s + 2 < 8) {
      const int pb = (s + 2) % 3;
      xraw[pb][0][0] = *(const float4*)(xr0 + (s + 2) * 32);
      xraw[pb][0][1] = *(const float4*)(xr0 + (s + 2) * 32 + 4);
      xraw[pb][1][0] = *(const float4*)(xr1 + (s + 2) * 32);
      xraw[pb][1][1] = *(const float4*)(xr1 + (s + 2) * 32 + 4);
    }
    i32x4 aw[4][3];
#pragma unroll
    for (int nt = 0; nt < 4; ++nt)
#pragma unroll
      for (int v = 0; v < 3; ++v)
        aw[nt][v] = *(const i32x4*)(wb + v * 16384 + nt * 4096 + s * 32);

    const int cb = s % 3;
    XFrags bx0 = split_x(xraw[cb][0][0], xraw[cb][0][1]);
    XFrags bx1 = split_x(xraw[cb][1][0], xraw[cb][1][1]);

#pragma unroll
    for (int nt = 0; nt < 4; ++nt) {
      acc[nt][0] = mf(aw[nt][0], bx0.h, acc[nt][0]);
      acc[nt][0] = mf(aw[nt][0], bx0.m, acc[nt][0]);
      acc[nt][0] = mf(aw[nt][1], bx0.h, acc[nt][0]);
      acc[nt][0] = mf(aw[nt][0], bx0.l, acc[nt][0]);
      acc[nt][0] = mf(aw[nt][1], bx0.m, acc[nt][0]);
      acc[nt][0] = mf(aw[nt][2], bx0.h, acc[nt][0]);
      acc[nt][1] = mf(aw[nt][0], bx1.h, acc[nt][1]);
      acc[nt][1] = mf(aw[nt][0], bx1.m, acc[nt][1]);
      acc[nt][1] = mf(aw[nt][1], bx1.h, acc[nt][1]);
      acc[nt][1] = mf(aw[nt][0], bx1.l, acc[nt][1]);
      acc[nt][1] = mf(aw[nt][1], bx1.m, acc[nt][1]);
      acc[nt][1] = mf(aw[nt][2], bx1.h, acc[nt][1]);
    }
  }

  // epilogue: D col=token(le), row=expert=nt*16+4*lg+j. LOGIT-domain select.
#pragma unroll
  for (int tt = 0; tt < 2; ++tt) {
    float l[16];
#pragma unroll
    for (int nt = 0; nt < 4; ++nt)
#pragma unroll
      for (int j = 0; j < 4; ++j) l[nt * 4 + j] = acc[nt][tt][j];

    float g0 = l[0], g1 = l[8];
#pragma unroll
    for (int j = 1; j < 8; ++j) {
      g0 = fmaxf(g0, l[j]);
      g1 = fmaxf(g1, l[8 + j]);
    }
    g0 = fmaxf(g0, __shfl_xor(g0, 16));
    g0 = fmaxf(g0, __shfl_xor(g0, 32));
    g1 = fmaxf(g1, __shfl_xor(g1, 16));
    g1 = fmaxf(g1, __shfl_xor(g1, 32));
    const int g = (g1 > g0) ? 1 : 0;  // tie -> group 0
    const float m = fmaxf(g0, g1);

    float sum = 0.f;
#pragma unroll
    for (int k = 0; k < 16; ++k) sum += __expf(l[k] - m);
    sum += __shfl_xor(sum, 16);
    sum += __shfl_xor(sum, 32);
    const float inv = 1.0f / sum;

    float c[8];
    int ce[8];
#pragma unroll
    for (int j2 = 0; j2 < 8; ++j2) {
      c[j2] = l[g * 8 + j2];
      ce[j2] = (2 * g + (j2 >> 2)) * 16 + 4 * lg + (j2 & 3);
    }

    float v5[5];
    int e5[5];
#pragma unroll
    for (int it = 0; it < 5; ++it) {
      float bv = c[0];
      int be = ce[0];
#pragma unroll
      for (int j2 = 1; j2 < 8; ++j2) {  // strict > keeps lowest index
        bool gt = c[j2] > bv;
        bv = gt ? c[j2] : bv;
        be = gt ? ce[j2] : be;
      }
#pragma unroll
      for (int st = 0; st < 2; ++st) {
        int msk = 16 << st;
        float ov = __shfl_xor(bv, msk);
        int oe = __shfl_xor(be, msk);
        bool tk = (ov > bv) || (ov == bv && oe < be);
        bv = tk ? ov : bv;
        be = tk ? oe : be;
      }
      v5[it] = bv;
      e5[it] = be;
#pragma unroll
      for (int j2 = 0; j2 < 8; ++j2)
        c[j2] = (ce[j2] == be) ? -3.0e38f : c[j2];
    }

    float ming = fabsf(g0 - g1);
#pragma unroll
    for (int it = 0; it < 4; ++it) ming = fminf(ming, v5[it] - v5[it + 1]);

    if (lg == 0) {
      size_t trow = (size_t)tokbase + tt * 16 + le;
      *(float4*)&out[trow * 4] =
          make_float4(__expf(v5[0] - m) * inv, __expf(v5[1] - m) * inv,
                      __expf(v5[2] - m) * inv, __expf(v5[3] - m) * inv);
      *(float4*)&out[(size_t)T * 4 + trow * 4] = make_float4(
          (float)e5[0], (float)e5[1], (float)e5[2], (float)e5[3]);
      if (ming < DELTA) {
        int p = atomicAdd(meta, 1);
        if (p < cap) list[p] = (int)trow;
      }
    }
  }
}

// exact recompute of flagged tokens: one wave per token, lane = expert.
__global__ __launch_bounds__(64) void fix_kernel(
    const float* __restrict__ x, const float* __restrict__ W,
    float* __restrict__ out, const int* __restrict__ meta,
    const int* __restrict__ list, int cap, int T) {
  const int e = threadIdx.x;
  int cnt = meta[0];
  cnt = cnt < cap ? cnt : cap;
  for (int i = blockIdx.x; i < cnt; i += gridDim.x) {
    const int tok = list[i];
    const float* xr = x + (size_t)tok * 256;
    const float* wr = W + (size_t)e * 256;
    float acc = 0.f;
#pragma unroll 8
    for (int d = 0; d < 256; d += 4) {  // single-acc ascending-d fmaf chain
      float4 xv = *(const float4*)(xr + d);
      float4 wv = *(const float4*)(wr + d);
      acc = fmaf(xv.x, wv.x, acc);
      acc = fmaf(xv.y, wv.y, acc);
      acc = fmaf(xv.z, wv.z, acc);
      acc = fmaf(xv.w, wv.w, acc);
    }
    // group maxima (exact, order-free)
    float gm = acc;
#pragma unroll
    for (int st = 0; st < 5; ++st) gm = fmaxf(gm, __shfl_xor(gm, 1 << st));
    float om = __shfl_xor(gm, 32);
    float g0 = (e < 32) ? gm : om;
    float g1 = (e < 32) ? om : gm;
    const int g = (g1 > g0) ? 1 : 0;
    const float m = fmaxf(g0, g1);
    float sum = __expf(acc - m);
#pragma unroll
    for (int st = 0; st < 6; ++st) sum += __shfl_xor(sum, 1 << st);
    const float inv = 1.0f / sum;

    float cand = ((e >> 5) == g) ? acc : -3.0e38f;
    float w4[4], i4[4];
#pragma unroll
    for (int it = 0; it < 4; ++it) {
      float bv = cand;
      int be = e;
#pragma unroll
      for (int st = 0; st < 6; ++st) {
        int msk = 1 << st;
        float ov = __shfl_xor(bv, msk);
        int oe = __shfl_xor(be, msk);
        bool tk = (ov > bv) || (ov == bv && oe < be);
        bv = tk ? ov : bv;
        be = tk ? oe : be;
      }
      w4[it] = __expf(bv - m) * inv;
      i4[it] = (float)be;
      if (e == be) cand = -3.0e38f;
    }
    if (e == 0) {
      *(float4*)&out[(size_t)tok * 4] =
          make_float4(w4[0], w4[1], w4[2], w4[3]);
      *(float4*)&out[(size_t)T * 4 + (size_t)tok * 4] =
          make_float4(i4[0], i4[1], i4[2], i4[3]);
    }
  }
}

extern "C" void kernel_launch(void* const* d_in, const int* in_sizes, int n_in,
                              void* d_out, int out_size, void* d_ws,
                              size_t ws_size, hipStream_t stream) {
  const float* x = (const float*)d_in[0];
  const float* W = (const float*)d_in[1];
  float* out = (float*)d_out;
  int T = in_sizes[0] / 256;  // D = 256
  int nW = in_sizes[1];       // 16384
  int* meta = (int*)d_ws;
  unsigned short* wsp = (unsigned short*)((char*)d_ws + SPLIT_OFF);
  int* list = (int*)((char*)d_ws + LIST_OFF);
  int cap =
      (ws_size > LIST_OFF + 4) ? (int)((ws_size - LIST_OFF) / 4) : 0;
  hipLaunchKernelGGL(zero_meta, dim3(1), dim3(1), 0, stream, meta);
  hipLaunchKernelGGL(split_w, dim3((nW + 255) / 256), dim3(256), 0, stream, W,
                     wsp, nW);
  hipLaunchKernelGGL(gate_kernel, dim3(T / 128), dim3(256), 0, stream, x, wsp,
                     out, meta, list, cap, T);
  hipLaunchKernelGGL(fix_kernel, dim3(1024), dim3(64), 0, stream, x, W, out,
                     meta, list, cap, T);
}

// Round 5
// 185.590 us; speedup vs baseline: 12.4004x; 1.6686x over previous
//
#include <hip/hip_runtime.h>
#include <hip/hip_bf16.h>
#include <stdint.h>

// MoE gate: T=524288, D=256, E=64, groups=2x32, topk=4.
// Pass 1: logits^T = W @ x^T via mfma_f32_16x16x32_bf16, exact 3-way bf16
//   truncation split (6 cross terms). x staged global->LDS (async
//   global_load_lds, double-buffered, XOR bank swizzle via pre-swizzled
//   global source). W pre-split into lane-major 1KB fragments (L2-hot,
//   coalesced dwordx4 loads with immediate offsets). Margin-flagged tokens
//   appended to a fix list.
// Pass 2: flagged tokens (~0.5%) recomputed with np-order-exact f32 chain.

typedef __attribute__((ext_vector_type(8))) short bf16x8;
typedef __attribute__((ext_vector_type(4))) float f32x4;
typedef __attribute__((ext_vector_type(4))) int i32x4;

#define SPLIT_OFF 1024
#define LIST_OFF 102400
#define DELTA 5e-5f

__device__ __forceinline__ f32x4 mf(const i32x4& a, const i32x4& b,
                                    const f32x4& c) {
  return __builtin_amdgcn_mfma_f32_16x16x32_bf16(
      __builtin_bit_cast(bf16x8, a), __builtin_bit_cast(bf16x8, b), c, 0, 0, 0);
}

// low short = hi16(e0), high short = hi16(e1)
__device__ __forceinline__ int packhi(unsigned e0, unsigned e1) {
  return (int)__builtin_amdgcn_perm(e1, e0, 0x07060302u);
}

__device__ __forceinline__ void gload16(const void* g, void* l) {
  __builtin_amdgcn_global_load_lds(
      (const __attribute__((address_space(1))) void*)g,
      (__attribute__((address_space(3))) void*)l, 16, 0, 0);
}

__global__ void zero_meta(int* meta) { meta[0] = 0; }

// Exact truncation split of W into 3 bf16 levels, written in MFMA
// A-fragment order: frag(v,nt,s) is 1KB, inside: lane(=lg*16+le)*16B holds
// W_v[e=nt*16+le][k=s*32+lg*8 .. +8].
__global__ void split_w(const float* __restrict__ W,
                        unsigned short* __restrict__ ws, int n) {
  int i = blockIdx.x * 256 + threadIdx.x;
  if (i >= n) return;
  float w = W[i];
  unsigned u = __float_as_uint(w);
  unsigned uh = u & 0xFFFF0000u;
  float rf = w - __uint_as_float(uh);
  unsigned um = __float_as_uint(rf) & 0xFFFF0000u;
  float lf = rf - __uint_as_float(um);
  unsigned short lv[3];
  lv[0] = (unsigned short)(uh >> 16);
  lv[1] = (unsigned short)(um >> 16);
  lv[2] = (unsigned short)(__float_as_uint(lf) >> 16);
  int e = i >> 8, k = i & 255;
  int nt = e >> 4, le = e & 15;
  int s = k >> 5, lg = (k >> 3) & 3, kk = k & 7;
#pragma unroll
  for (int v = 0; v < 3; ++v)
    ws[((((v * 4 + nt) * 8 + s) * 64) + lg * 16 + le) * 8 + kk] = lv[v];
}

struct XFrags { i32x4 h, m, l; };

__device__ __forceinline__ XFrags split_x(const float4& q0, const float4& q1) {
  float xs[8] = {q0.x, q0.y, q0.z, q0.w, q1.x, q1.y, q1.z, q1.w};
  unsigned hu[8], mu[8], lu[8];
#pragma unroll
  for (int j = 0; j < 8; ++j) {
    unsigned u = __float_as_uint(xs[j]);
    unsigned uh = u & 0xFFFF0000u;
    float r = xs[j] - __uint_as_float(uh);
    unsigned um = __float_as_uint(r) & 0xFFFF0000u;
    float lf = r - __uint_as_float(um);
    hu[j] = u;
    mu[j] = __float_as_uint(r);
    lu[j] = __float_as_uint(lf);
  }
  XFrags f;
#pragma unroll
  for (int wd = 0; wd < 4; ++wd) {
    f.h[wd] = packhi(hu[2 * wd], hu[2 * wd + 1]);
    f.m[wd] = packhi(mu[2 * wd], mu[2 * wd + 1]);
    f.l[wd] = packhi(lu[2 * wd], lu[2 * wd + 1]);
  }
  return f;
}

__global__ __launch_bounds__(256, 2) void gate_kernel(
    const float* __restrict__ x, const unsigned short* __restrict__ wsp,
    float* __restrict__ out, int* __restrict__ meta, int* __restrict__ list,
    int cap, int T) {
  // X staging: [2 bufs][128 rows][8 slots of 16B], slots XOR-swizzled by row.
  __shared__ float XS[2][4096];  // 32 KB

  const int t = threadIdx.x;
  const int lane = t & 63;
  const int wid = t >> 6;
  const int le = lane & 15;
  const int lg = lane >> 4;
  const int tokbase = blockIdx.x * 128;

  // staging sources: phys slot S holds logical slot (S&7)^(row&7) of row S>>3
  const float* xsrc[4];
#pragma unroll
  for (int q = 0; q < 4; ++q) {
    int S = q * 256 + t;
    int row = S >> 3, p = S & 7;
    int l = p ^ (row & 7);
    xsrc[q] = x + (size_t)(tokbase + row) * 256 + l * 4;
  }

  auto stage = [&](int bi, int c) {
#pragma unroll
    for (int q = 0; q < 4; ++q)
      gload16(xsrc[q] + c * 32, &XS[bi][(q * 256 + t) * 4]);
  };

  const unsigned short* wfrag = wsp + lane * 8;

  f32x4 acc[4][2];
#pragma unroll
  for (int nt = 0; nt < 4; ++nt)
#pragma unroll
    for (int tt = 0; tt < 2; ++tt) acc[nt][tt] = (f32x4)0.0f;

  stage(0, 0);
  __syncthreads();

#pragma unroll
  for (int c = 0; c < 8; ++c) {
    if (c < 7) stage((c + 1) & 1, c + 1);  // async prefetch of next k-chunk

    // W A-fragments for this k-chunk (L2-hot, coalesced, issued early)
    i32x4 aw[3][4];
#pragma unroll
    for (int v = 0; v < 3; ++v)
#pragma unroll
      for (int nt = 0; nt < 4; ++nt)
        aw[v][nt] =
            *(const i32x4*)(wfrag + (((v * 4 + nt) * 8 + c) << 9));

    // B raw f32 from LDS (swizzled slots -> 2-way bank = free)
    const float* Xb = XS[c & 1];
    const int r0 = wid * 32 + le;
    const int r1 = r0 + 16;
    float4 raw00 = *(const float4*)&Xb[(r0 * 8 + ((lg * 2) ^ (r0 & 7))) * 4];
    float4 raw01 =
        *(const float4*)&Xb[(r0 * 8 + ((lg * 2 + 1) ^ (r0 & 7))) * 4];
    float4 raw10 = *(const float4*)&Xb[(r1 * 8 + ((lg * 2) ^ (r1 & 7))) * 4];
    float4 raw11 =
        *(const float4*)&Xb[(r1 * 8 + ((lg * 2 + 1) ^ (r1 & 7))) * 4];

    XFrags b0 = split_x(raw00, raw01);
    XFrags b1 = split_x(raw10, raw11);

#pragma unroll
    for (int nt = 0; nt < 4; ++nt) {
      acc[nt][0] = mf(aw[0][nt], b0.h, acc[nt][0]);
      acc[nt][0] = mf(aw[0][nt], b0.m, acc[nt][0]);
      acc[nt][0] = mf(aw[1][nt], b0.h, acc[nt][0]);
      acc[nt][0] = mf(aw[0][nt], b0.l, acc[nt][0]);
      acc[nt][0] = mf(aw[1][nt], b0.m, acc[nt][0]);
      acc[nt][0] = mf(aw[2][nt], b0.h, acc[nt][0]);
      acc[nt][1] = mf(aw[0][nt], b1.h, acc[nt][1]);
      acc[nt][1] = mf(aw[0][nt], b1.m, acc[nt][1]);
      acc[nt][1] = mf(aw[1][nt], b1.h, acc[nt][1]);
      acc[nt][1] = mf(aw[0][nt], b1.l, acc[nt][1]);
      acc[nt][1] = mf(aw[1][nt], b1.m, acc[nt][1]);
      acc[nt][1] = mf(aw[2][nt], b1.h, acc[nt][1]);
    }
    __syncthreads();
  }

  // epilogue: D col=token(le), row=expert=nt*16+4*lg+j. LOGIT-domain select.
#pragma unroll
  for (int tt = 0; tt < 2; ++tt) {
    float l[16];
#pragma unroll
    for (int nt = 0; nt < 4; ++nt)
#pragma unroll
      for (int j = 0; j < 4; ++j) l[nt * 4 + j] = acc[nt][tt][j];

    float g0 = l[0], g1 = l[8];
#pragma unroll
    for (int j = 1; j < 8; ++j) {
      g0 = fmaxf(g0, l[j]);
      g1 = fmaxf(g1, l[8 + j]);
    }
    g0 = fmaxf(g0, __shfl_xor(g0, 16));
    g0 = fmaxf(g0, __shfl_xor(g0, 32));
    g1 = fmaxf(g1, __shfl_xor(g1, 16));
    g1 = fmaxf(g1, __shfl_xor(g1, 32));
    const int g = (g1 > g0) ? 1 : 0;  // tie -> group 0
    const float m = fmaxf(g0, g1);

    float sum = 0.f;
#pragma unroll
    for (int k = 0; k < 16; ++k) sum += __expf(l[k] - m);
    sum += __shfl_xor(sum, 16);
    sum += __shfl_xor(sum, 32);
    const float inv = 1.0f / sum;

    float c[8];
    int ce[8];
#pragma unroll
    for (int j2 = 0; j2 < 8; ++j2) {
      c[j2] = l[g * 8 + j2];
      ce[j2] = (2 * g + (j2 >> 2)) * 16 + 4 * lg + (j2 & 3);
    }

    float v5[5];
    int e5[5];
#pragma unroll
    for (int it = 0; it < 5; ++it) {
      float bv = c[0];
      int be = ce[0];
#pragma unroll
      for (int j2 = 1; j2 < 8; ++j2) {  // strict > keeps lowest index
        bool gt = c[j2] > bv;
        bv = gt ? c[j2] : bv;
        be = gt ? ce[j2] : be;
      }
#pragma unroll
      for (int st = 0; st < 2; ++st) {
        int msk = 16 << st;
        float ov = __shfl_xor(bv, msk);
        int oe = __shfl_xor(be, msk);
        bool tk = (ov > bv) || (ov == bv && oe < be);
        bv = tk ? ov : bv;
        be = tk ? oe : be;
      }
      v5[it] = bv;
      e5[it] = be;
#pragma unroll
      for (int j2 = 0; j2 < 8; ++j2)
        c[j2] = (ce[j2] == be) ? -3.0e38f : c[j2];
    }

    float ming = fabsf(g0 - g1);
#pragma unroll
    for (int it = 0; it < 4; ++it) ming = fminf(ming, v5[it] - v5[it + 1]);

    if (lg == 0) {
      size_t trow = (size_t)tokbase + wid * 32 + tt * 16 + le;
      *(float4*)&out[trow * 4] =
          make_float4(__expf(v5[0] - m) * inv, __expf(v5[1] - m) * inv,
                      __expf(v5[2] - m) * inv, __expf(v5[3] - m) * inv);
      *(float4*)&out[(size_t)T * 4 + trow * 4] = make_float4(
          (float)e5[0], (float)e5[1], (float)e5[2], (float)e5[3]);
      if (ming < DELTA) {
        int p = atomicAdd(meta, 1);
        if (p < cap) list[p] = (int)trow;
      }
    }
  }
}

// exact recompute of flagged tokens: one wave per token, lane = expert.
__global__ __launch_bounds__(64) void fix_kernel(
    const float* __restrict__ x, const float* __restrict__ W,
    float* __restrict__ out, const int* __restrict__ meta,
    const int* __restrict__ list, int cap, int T) {
  const int e = threadIdx.x;
  int cnt = meta[0];
  cnt = cnt < cap ? cnt : cap;
  for (int i = blockIdx.x; i < cnt; i += gridDim.x) {
    const int tok = list[i];
    const float* xr = x + (size_t)tok * 256;
    const float* wr = W + (size_t)e * 256;
    float acc = 0.f;
#pragma unroll 8
    for (int d = 0; d < 256; d += 4) {  // single-acc ascending-d fmaf chain
      float4 xv = *(const float4*)(xr + d);
      float4 wv = *(const float4*)(wr + d);
      acc = fmaf(xv.x, wv.x, acc);
      acc = fmaf(xv.y, wv.y, acc);
      acc = fmaf(xv.z, wv.z, acc);
      acc = fmaf(xv.w, wv.w, acc);
    }
    float gm = acc;
#pragma unroll
    for (int st = 0; st < 5; ++st) gm = fmaxf(gm, __shfl_xor(gm, 1 << st));
    float om = __shfl_xor(gm, 32);
    float g0 = (e < 32) ? gm : om;
    float g1 = (e < 32) ? om : gm;
    const int g = (g1 > g0) ? 1 : 0;
    const float m = fmaxf(g0, g1);
    float sum = __expf(acc - m);
#pragma unroll
    for (int st = 0; st < 6; ++st) sum += __shfl_xor(sum, 1 << st);
    const float inv = 1.0f / sum;

    float cand = ((e >> 5) == g) ? acc : -3.0e38f;
    float w4[4], i4[4];
#pragma unroll
    for (int it = 0; it < 4; ++it) {
      float bv = cand;
      int be = e;
#pragma unroll
      for (int st = 0; st < 6; ++st) {
        int msk = 1 << st;
        float ov = __shfl_xor(bv, msk);
        int oe = __shfl_xor(be, msk);
        bool tk = (ov > bv) || (ov == bv && oe < be);
        bv = tk ? ov : bv;
        be = tk ? oe : be;
      }
      w4[it] = __expf(bv - m) * inv;
      i4[it] = (float)be;
      if (e == be) cand = -3.0e38f;
    }
    if (e == 0) {
      *(float4*)&out[(size_t)tok * 4] =
          make_float4(w4[0], w4[1], w4[2], w4[3]);
      *(float4*)&out[(size_t)T * 4 + (size_t)tok * 4] =
          make_float4(i4[0], i4[1], i4[2], i4[3]);
    }
  }
}

extern "C" void kernel_launch(void* const* d_in, const int* in_sizes, int n_in,
                              void* d_out, int out_size, void* d_ws,
                              size_t ws_size, hipStream_t stream) {
  const float* x = (const float*)d_in[0];
  const float* W = (const float*)d_in[1];
  float* out = (float*)d_out;
  int T = in_sizes[0] / 256;  // D = 256
  int nW = in_sizes[1];       // 16384
  int* meta = (int*)d_ws;
  unsigned short* wsp = (unsigned short*)((char*)d_ws + SPLIT_OFF);
  int* list = (int*)((char*)d_ws + LIST_OFF);
  int cap = (ws_size > LIST_OFF + 4) ? (int)((ws_size - LIST_OFF) / 4) : 0;
  hipLaunchKernelGGL(zero_meta, dim3(1), dim3(1), 0, stream, meta);
  hipLaunchKernelGGL(split_w, dim3((nW + 255) / 256), dim3(256), 0, stream, W,
                     wsp, nW);
  hipLaunchKernelGGL(gate_kernel, dim3(T / 128), dim3(256), 0, stream, x, wsp,
                     out, meta, list, cap, T);
  hipLaunchKernelGGL(fix_kernel, dim3(1024), dim3(64), 0, stream, x, W, out,
                     meta, list, cap, T);
}

// Round 6
// 167.586 us; speedup vs baseline: 13.7326x; 1.1074x over previous
//
#include <hip/hip_runtime.h>
#include <hip/hip_bf16.h>
#include <stdint.h>

// MoE gate: T=524288, D=256, E=64, groups=2x32, topk=4.
// Pass 1: logits^T = W @ x^T via mfma_f32_16x16x32_bf16. W split into 2 bf16
//   levels (h,m), x into 3 (h,m,l); 5 cross terms kept (dropped-term sigma
//   ~5e-6 << DELTA). Fully barrier-free: no LDS; x and W flow global->reg
//   through inline-asm global_load_dwordx4 with manual counted
//   s_waitcnt vmcnt(N) (never 0 in steady state) -> loads always in flight.
// Pass 2: tokens with selection margin < DELTA recomputed exactly (np-order
//   fmaf chain) by fix_kernel (~0.5% of tokens).

typedef __attribute__((ext_vector_type(8))) short bf16x8;
typedef __attribute__((ext_vector_type(4))) float f32x4;
typedef __attribute__((ext_vector_type(4))) int i32x4;

#define SPLIT_OFF 1024
#define LIST_OFF 102400
#define DELTA 5e-5f

__device__ __forceinline__ f32x4 mf(const i32x4& a, const i32x4& b,
                                    const f32x4& c) {
  return __builtin_amdgcn_mfma_f32_16x16x32_bf16(
      __builtin_bit_cast(bf16x8, a), __builtin_bit_cast(bf16x8, b), c, 0, 0, 0);
}

// low short = hi16(e0), high short = hi16(e1)
__device__ __forceinline__ int packhi(unsigned e0, unsigned e1) {
  return (int)__builtin_amdgcn_perm(e1, e0, 0x07060302u);
}

__global__ void zero_meta(int* meta) { meta[0] = 0; }

// W -> 2 bf16 levels (h, m), packed in MFMA A-fragment chunk-major layout:
// frag(c, q=v*4+nt) is 1KB; lane(=lg*16+le)*16B holds
// W_v[e=nt*16+le][k=c*32+lg*8 .. +8].
__global__ void split_w(const float* __restrict__ W,
                        unsigned short* __restrict__ ws, int n) {
  int i = blockIdx.x * 256 + threadIdx.x;
  if (i >= n) return;
  float w = W[i];
  unsigned u = __float_as_uint(w);
  unsigned uh = u & 0xFFFF0000u;
  float rf = w - __uint_as_float(uh);  // exact
  unsigned short lv[2];
  lv[0] = (unsigned short)(uh >> 16);
  lv[1] = (unsigned short)(__float_as_uint(rf) >> 16);
  int e = i >> 8, k = i & 255;
  int nt = e >> 4, le = e & 15;
  int c = k >> 5, lg = (k >> 3) & 3, kk = k & 7;
  int lane = lg * 16 + le;
#pragma unroll
  for (int v = 0; v < 2; ++v)
    ws[(((c * 8 + v * 4 + nt) * 64) + lane) * 8 + kk] = lv[v];
}

struct XF { i32x4 h, m, l; };

__device__ __forceinline__ XF split_x(f32x4 a, f32x4 b) {
  float xs[8] = {a[0], a[1], a[2], a[3], b[0], b[1], b[2], b[3]};
  unsigned hu[8], mu[8], lu[8];
#pragma unroll
  for (int j = 0; j < 8; ++j) {
    unsigned u = __float_as_uint(xs[j]);
    unsigned uh = u & 0xFFFF0000u;
    float r = xs[j] - __uint_as_float(uh);  // exact
    unsigned um = __float_as_uint(r) & 0xFFFF0000u;
    float lf = r - __uint_as_float(um);  // exact
    hu[j] = u;
    mu[j] = __float_as_uint(r);
    lu[j] = __float_as_uint(lf);
  }
  XF f;
#pragma unroll
  for (int wd = 0; wd < 4; ++wd) {
    f.h[wd] = packhi(hu[2 * wd], hu[2 * wd + 1]);
    f.m[wd] = packhi(mu[2 * wd], mu[2 * wd + 1]);
    f.l[wd] = packhi(lu[2 * wd], lu[2 * wd + 1]);
  }
  return f;
}

// inline-asm global load: result valid only after the matching WAITV.
#define GL(dst, ptr, OFFSTR)                                       \
  asm volatile("global_load_dwordx4 %0, %1, off offset:" OFFSTR    \
               : "=v"(dst)                                         \
               : "v"(ptr))

#define WAITV(NSTR)                                         \
  do {                                                      \
    asm volatile("s_waitcnt vmcnt(" NSTR ")" ::: "memory"); \
    __builtin_amdgcn_sched_barrier(0);                      \
  } while (0)

__global__ __launch_bounds__(256, 2) void gate_kernel(
    const float* __restrict__ x, const unsigned short* __restrict__ wsp,
    float* __restrict__ out, int* __restrict__ meta, int* __restrict__ list,
    int cap, int T) {
  const int t = threadIdx.x;
  const int lane = t & 63;
  const int wid = t >> 6;
  const int le = lane & 15;  // token col / expert row within 16-tile
  const int lg = lane >> 4;  // k-quad group
  const int tokbase = blockIdx.x * 128 + wid * 32;

  const float* xa0 = x + (size_t)(tokbase + le) * 256 + lg * 8;
  const float* xa1 = xa0 + 16 * 256;
  const char* wl = (const char*)wsp + lane * 16;

  f32x4 xbuf[3][4];  // depth-2 x prefetch, static rotation
  i32x4 wbuf[2][8];  // depth-1 W prefetch
  f32x4 acc[4][2];
#pragma unroll
  for (int nt = 0; nt < 4; ++nt)
#pragma unroll
    for (int tt = 0; tt < 2; ++tt) acc[nt][tt] = (f32x4)0.0f;

#define STAGE_X(c)                                   \
  do {                                               \
    const float* p0_ = xa0 + (c) * 32;               \
    const float* p1_ = xa1 + (c) * 32;               \
    GL(xbuf[(c) % 3][0], p0_, "0");                  \
    GL(xbuf[(c) % 3][1], p0_, "16");                 \
    GL(xbuf[(c) % 3][2], p1_, "0");                  \
    GL(xbuf[(c) % 3][3], p1_, "16");                 \
  } while (0)

#define STAGE_W(c)                                   \
  do {                                               \
    const char* pA_ = wl + (c) * 8192;               \
    const char* pB_ = pA_ + 4096;                    \
    GL(wbuf[(c) & 1][0], pA_, "0");                  \
    GL(wbuf[(c) & 1][1], pA_, "1024");               \
    GL(wbuf[(c) & 1][2], pA_, "2048");               \
    GL(wbuf[(c) & 1][3], pA_, "3072");               \
    GL(wbuf[(c) & 1][4], pB_, "0");                  \
    GL(wbuf[(c) & 1][5], pB_, "1024");               \
    GL(wbuf[(c) & 1][6], pB_, "2048");               \
    GL(wbuf[(c) & 1][7], pB_, "3072");               \
  } while (0)

#define COMP(c)                                           \
  do {                                                    \
    XF b0 = split_x(xbuf[(c) % 3][0], xbuf[(c) % 3][1]);  \
    XF b1 = split_x(xbuf[(c) % 3][2], xbuf[(c) % 3][3]);  \
    _Pragma("unroll") for (int nt = 0; nt < 4; ++nt) {    \
      const i32x4 ah = wbuf[(c) & 1][nt];                 \
      const i32x4 am = wbuf[(c) & 1][4 + nt];             \
      acc[nt][0] = mf(ah, b0.h, acc[nt][0]);              \
      acc[nt][0] = mf(ah, b0.m, acc[nt][0]);              \
      acc[nt][0] = mf(am, b0.h, acc[nt][0]);              \
      acc[nt][0] = mf(am, b0.m, acc[nt][0]);              \
      acc[nt][0] = mf(ah, b0.l, acc[nt][0]);              \
      acc[nt][1] = mf(ah, b1.h, acc[nt][1]);              \
      acc[nt][1] = mf(ah, b1.m, acc[nt][1]);              \
      acc[nt][1] = mf(am, b1.h, acc[nt][1]);              \
      acc[nt][1] = mf(am, b1.m, acc[nt][1]);              \
      acc[nt][1] = mf(ah, b1.l, acc[nt][1]);              \
    }                                                     \
  } while (0)

  // prologue: x depth-2, W depth-1, all in flight before first wait
  STAGE_X(0);
  STAGE_X(1);
  STAGE_W(0);
  // steady state: issue W(c+1), x(c+2); wait with counted vmcnt; compute c.
  // N = ops younger than W(c) at the wait (in-order retire, m135).
  STAGE_W(1); STAGE_X(2); WAITV("12"); COMP(0);
  STAGE_W(2); STAGE_X(3); WAITV("16"); COMP(1);
  STAGE_W(3); STAGE_X(4); WAITV("16"); COMP(2);
  STAGE_W(4); STAGE_X(5); WAITV("16"); COMP(3);
  STAGE_W(5); STAGE_X(6); WAITV("16"); COMP(4);
  STAGE_W(6); STAGE_X(7); WAITV("16"); COMP(5);
  STAGE_W(7); WAITV("12"); COMP(6);
  WAITV("0"); COMP(7);

  // epilogue: D col=token(le), row=expert=nt*16+4*lg+j. LOGIT-domain select.
#pragma unroll
  for (int tt = 0; tt < 2; ++tt) {
    float l[16];
#pragma unroll
    for (int nt = 0; nt < 4; ++nt)
#pragma unroll
      for (int j = 0; j < 4; ++j) l[nt * 4 + j] = acc[nt][tt][j];

    float g0 = l[0], g1 = l[8];
#pragma unroll
    for (int j = 1; j < 8; ++j) {
      g0 = fmaxf(g0, l[j]);
      g1 = fmaxf(g1, l[8 + j]);
    }
    g0 = fmaxf(g0, __shfl_xor(g0, 16));
    g0 = fmaxf(g0, __shfl_xor(g0, 32));
    g1 = fmaxf(g1, __shfl_xor(g1, 16));
    g1 = fmaxf(g1, __shfl_xor(g1, 32));
    const int g = (g1 > g0) ? 1 : 0;  // tie -> group 0
    const float m = fmaxf(g0, g1);

    float sum = 0.f;
#pragma unroll
    for (int k = 0; k < 16; ++k) sum += __expf(l[k] - m);
    sum += __shfl_xor(sum, 16);
    sum += __shfl_xor(sum, 32);
    const float inv = 1.0f / sum;

    float c[8];
    int ce[8];
#pragma unroll
    for (int j2 = 0; j2 < 8; ++j2) {
      c[j2] = l[g * 8 + j2];
      ce[j2] = (2 * g + (j2 >> 2)) * 16 + 4 * lg + (j2 & 3);
    }

    float v5[5];
    int e5[5];
#pragma unroll
    for (int it = 0; it < 5; ++it) {
      float bv = c[0];
      int be = ce[0];
#pragma unroll
      for (int j2 = 1; j2 < 8; ++j2) {  // strict > keeps lowest index
        bool gt = c[j2] > bv;
        bv = gt ? c[j2] : bv;
        be = gt ? ce[j2] : be;
      }
#pragma unroll
      for (int st = 0; st < 2; ++st) {
        int msk = 16 << st;
        float ov = __shfl_xor(bv, msk);
        int oe = __shfl_xor(be, msk);
        bool tk = (ov > bv) || (ov == bv && oe < be);
        bv = tk ? ov : bv;
        be = tk ? oe : be;
      }
      v5[it] = bv;
      e5[it] = be;
#pragma unroll
      for (int j2 = 0; j2 < 8; ++j2)
        c[j2] = (ce[j2] == be) ? -3.0e38f : c[j2];
    }

    float ming = fabsf(g0 - g1);
#pragma unroll
    for (int it = 0; it < 4; ++it) ming = fminf(ming, v5[it] - v5[it + 1]);

    if (lg == 0) {
      size_t trow = (size_t)tokbase + tt * 16 + le;
      *(float4*)&out[trow * 4] =
          make_float4(__expf(v5[0] - m) * inv, __expf(v5[1] - m) * inv,
                      __expf(v5[2] - m) * inv, __expf(v5[3] - m) * inv);
      *(float4*)&out[(size_t)T * 4 + trow * 4] = make_float4(
          (float)e5[0], (float)e5[1], (float)e5[2], (float)e5[3]);
      if (ming < DELTA) {
        int p = atomicAdd(meta, 1);
        if (p < cap) list[p] = (int)trow;
      }
    }
  }
}

// exact recompute of flagged tokens: one wave per token, lane = expert.
__global__ __launch_bounds__(64) void fix_kernel(
    const float* __restrict__ x, const float* __restrict__ W,
    float* __restrict__ out, const int* __restrict__ meta,
    const int* __restrict__ list, int cap, int T) {
  const int e = threadIdx.x;
  int cnt = meta[0];
  cnt = cnt < cap ? cnt : cap;
  for (int i = blockIdx.x; i < cnt; i += gridDim.x) {
    const int tok = list[i];
    const float* xr = x + (size_t)tok * 256;
    const float* wr = W + (size_t)e * 256;
    float acc = 0.f;
#pragma unroll 8
    for (int d = 0; d < 256; d += 4) {  // single-acc ascending-d fmaf chain
      float4 xv = *(const float4*)(xr + d);
      float4 wv = *(const float4*)(wr + d);
      acc = fmaf(xv.x, wv.x, acc);
      acc = fmaf(xv.y, wv.y, acc);
      acc = fmaf(xv.z, wv.z, acc);
      acc = fmaf(xv.w, wv.w, acc);
    }
    float gm = acc;
#pragma unroll
    for (int st = 0; st < 5; ++st) gm = fmaxf(gm, __shfl_xor(gm, 1 << st));
    float om = __shfl_xor(gm, 32);
    float g0 = (e < 32) ? gm : om;
    float g1 = (e < 32) ? om : gm;
    const int g = (g1 > g0) ? 1 : 0;
    const float m = fmaxf(g0, g1);
    float sum = __expf(acc - m);
#pragma unroll
    for (int st = 0; st < 6; ++st) sum += __shfl_xor(sum, 1 << st);
    const float inv = 1.0f / sum;

    float cand = ((e >> 5) == g) ? acc : -3.0e38f;
    float w4[4], i4[4];
#pragma unroll
    for (int it = 0; it < 4; ++it) {
      float bv = cand;
      int be = e;
#pragma unroll
      for (int st = 0; st < 6; ++st) {
        int msk = 1 << st;
        float ov = __shfl_xor(bv, msk);
        int oe = __shfl_xor(be, msk);
        bool tk = (ov > bv) || (ov == bv && oe < be);
        bv = tk ? ov : bv;
        be = tk ? oe : be;
      }
      w4[it] = __expf(bv - m) * inv;
      i4[it] = (float)be;
      if (e == be) cand = -3.0e38f;
    }
    if (e == 0) {
      *(float4*)&out[(size_t)tok * 4] = make_float4(w4[0], w4[1], w4[2], w4[3]);
      *(float4*)&out[(size_t)T * 4 + (size_t)tok * 4] =
          make_float4(i4[0], i4[1], i4[2], i4[3]);
    }
  }
}

extern "C" void kernel_launch(void* const* d_in, const int* in_sizes, int n_in,
                              void* d_out, int out_size, void* d_ws,
                              size_t ws_size, hipStream_t stream) {
  const float* x = (const float*)d_in[0];
  const float* W = (const float*)d_in[1];
  float* out = (float*)d_out;
  int T = in_sizes[0] / 256;  // D = 256
  int nW = in_sizes[1];       // 16384
  int* meta = (int*)d_ws;
  unsigned short* wsp = (unsigned short*)((char*)d_ws + SPLIT_OFF);
  int* list = (int*)((char*)d_ws + LIST_OFF);
  int cap = (ws_size > LIST_OFF + 4) ? (int)((ws_size - LIST_OFF) / 4) : 0;
  hipLaunchKernelGGL(zero_meta, dim3(1), dim3(1), 0, stream, meta);
  hipLaunchKernelGGL(split_w, dim3((nW + 255) / 256), dim3(256), 0, stream, W,
                     wsp, nW);
  hipLaunchKernelGGL(gate_kernel, dim3(T / 128), dim3(256), 0, stream, x, wsp,
                     out, meta, list, cap, T);
  hipLaunchKernelGGL(fix_kernel, dim3(1024), dim3(64), 0, stream, x, W, out,
                     meta, list, cap, T);
}

// Round 7
// 148.115 us; speedup vs baseline: 15.5379x; 1.1315x over previous
//
#include <hip/hip_runtime.h>
#include <hip/hip_bf16.h>
#include <stdint.h>

// MoE gate: T=524288, D=256, E=64, groups=2x32, topk=4.
// Pass 1: logits^T = W @ x^T via mfma_f32_16x16x32_bf16. W and x each split
//   into 2 bf16 truncation levels; 4 cross terms (hh,hm,mh,mm); dropped-term
//   sigma ~7e-6 << DELTA=1e-4. W-split staged once per block into LDS
//   (global_load_lds, one barrier); per-chunk W via ds_read_b128. x flows
//   global->reg (inline asm, depth-2 prefetch, counted s_waitcnt vmcnt --
//   never 0 in steady state; vmem queue contains ONLY x loads).
// Pass 2: tokens with selection margin < DELTA recomputed exactly (np-order
//   fmaf chain) by fix_kernel (~1% of tokens).

typedef __attribute__((ext_vector_type(8))) short bf16x8;
typedef __attribute__((ext_vector_type(4))) float f32x4;
typedef __attribute__((ext_vector_type(4))) int i32x4;

#define SPLIT_OFF 1024
#define LIST_OFF 102400
#define DELTA 1e-4f

__device__ __forceinline__ f32x4 mf(const i32x4& a, const i32x4& b,
                                    const f32x4& c) {
  return __builtin_amdgcn_mfma_f32_16x16x32_bf16(
      __builtin_bit_cast(bf16x8, a), __builtin_bit_cast(bf16x8, b), c, 0, 0, 0);
}

// low short = hi16(e0), high short = hi16(e1)
__device__ __forceinline__ int packhi(unsigned e0, unsigned e1) {
  return (int)__builtin_amdgcn_perm(e1, e0, 0x07060302u);
}

__device__ __forceinline__ void gload16(const void* g, void* l) {
  __builtin_amdgcn_global_load_lds(
      (const __attribute__((address_space(1))) void*)g,
      (__attribute__((address_space(3))) void*)l, 16, 0, 0);
}

__global__ void zero_meta(int* meta) { meta[0] = 0; }

// W -> 2 bf16 truncation levels (h, m), packed in MFMA A-fragment
// chunk-major layout: frag(c, q=v*4+nt) is 1KB; lane(=lg*16+le)*16B holds
// W_v[e=nt*16+le][k=c*32+lg*8 .. +8].
__global__ void split_w(const float* __restrict__ W,
                        unsigned short* __restrict__ ws, int n) {
  int i = blockIdx.x * 256 + threadIdx.x;
  if (i >= n) return;
  float w = W[i];
  unsigned u = __float_as_uint(w);
  unsigned uh = u & 0xFFFF0000u;
  float rf = w - __uint_as_float(uh);  // exact
  unsigned short lv[2];
  lv[0] = (unsigned short)(uh >> 16);
  lv[1] = (unsigned short)(__float_as_uint(rf) >> 16);
  int e = i >> 8, k = i & 255;
  int nt = e >> 4, le = e & 15;
  int c = k >> 5, lg = (k >> 3) & 3, kk = k & 7;
  int lane = lg * 16 + le;
#pragma unroll
  for (int v = 0; v < 2; ++v)
    ws[(((c * 8 + v * 4 + nt) * 64) + lane) * 8 + kk] = lv[v];
}

struct XF2 { i32x4 h, m; };

__device__ __forceinline__ XF2 split2(f32x4 a, f32x4 b) {
  float xs[8] = {a[0], a[1], a[2], a[3], b[0], b[1], b[2], b[3]};
  XF2 f;
#pragma unroll
  for (int wd = 0; wd < 4; ++wd) {
    unsigned u0 = __float_as_uint(xs[2 * wd]);
    unsigned u1 = __float_as_uint(xs[2 * wd + 1]);
    f.h[wd] = packhi(u0, u1);
    float r0 = xs[2 * wd] - __uint_as_float(u0 & 0xFFFF0000u);      // exact
    float r1 = xs[2 * wd + 1] - __uint_as_float(u1 & 0xFFFF0000u);  // exact
    f.m[wd] = packhi(__float_as_uint(r0), __float_as_uint(r1));
  }
  return f;
}

// inline-asm global load: result valid only after the matching WAITV.
#define GL(dst, ptr, OFFSTR)                                    \
  asm volatile("global_load_dwordx4 %0, %1, off offset:" OFFSTR \
               : "=v"(dst)                                      \
               : "v"(ptr))

#define WAITV(NSTR)                                         \
  do {                                                      \
    asm volatile("s_waitcnt vmcnt(" NSTR ")" ::: "memory"); \
    __builtin_amdgcn_sched_barrier(0);                      \
  } while (0)

__global__ __launch_bounds__(256, 2) void gate_kernel(
    const float* __restrict__ x, const unsigned short* __restrict__ wsp,
    float* __restrict__ out, int* __restrict__ meta, int* __restrict__ list,
    int cap, int T) {
  __shared__ i32x4 WL[4096];  // 64 KB: W-split fragments, chunk-major

  const int t = threadIdx.x;
  const int lane = t & 63;
  const int wid = t >> 6;
  const int le = lane & 15;  // token col / expert row within 16-tile
  const int lg = lane >> 4;  // k-quad group
  const int tokbase = blockIdx.x * 256 + wid * 64;

  // ---- one-time W stage: ws (linear fragment layout) -> LDS ----
  {
    const char* wsrc = (const char*)wsp + t * 16;
    char* wdst = (char*)WL + t * 16;
#pragma unroll
    for (int i = 0; i < 16; ++i) gload16(wsrc + i * 4096, wdst + i * 4096);
  }
  WAITV("0");
  __syncthreads();

  const float* xa[4];
#pragma unroll
  for (int t4 = 0; t4 < 4; ++t4)
    xa[t4] = x + (size_t)(tokbase + t4 * 16 + le) * 256 + lg * 8;

  f32x4 xbuf[3][8];  // depth-2 x prefetch, static rotation
  f32x4 acc[4][4];   // [nt][tile]
#pragma unroll
  for (int nt = 0; nt < 4; ++nt)
#pragma unroll
    for (int t4 = 0; t4 < 4; ++t4) acc[nt][t4] = (f32x4)0.0f;

#define STAGE_X(c)                                   \
  do {                                               \
    _Pragma("unroll") for (int t4 = 0; t4 < 4; ++t4) { \
      const float* p_ = xa[t4] + (c) * 32;           \
      GL(xbuf[(c) % 3][2 * t4], p_, "0");            \
      GL(xbuf[(c) % 3][2 * t4 + 1], p_, "16");       \
    }                                                \
  } while (0)

#define ITER(c, NSTR)                                             \
  {                                                               \
    if ((c) < 6) STAGE_X((c) + 2);                                \
    i32x4 wr[8];                                                  \
    _Pragma("unroll") for (int q = 0; q < 8; ++q)                 \
        wr[q] = WL[(((c) * 8 + q) << 6) + lane];                  \
    WAITV(NSTR);                                                  \
    _Pragma("unroll") for (int t4 = 0; t4 < 4; ++t4) {            \
      XF2 b = split2(xbuf[(c) % 3][2 * t4], xbuf[(c) % 3][2 * t4 + 1]); \
      _Pragma("unroll") for (int nt = 0; nt < 4; ++nt) {          \
        acc[nt][t4] = mf(wr[nt], b.h, acc[nt][t4]);               \
        acc[nt][t4] = mf(wr[nt], b.m, acc[nt][t4]);               \
        acc[nt][t4] = mf(wr[4 + nt], b.h, acc[nt][t4]);           \
        acc[nt][t4] = mf(wr[4 + nt], b.m, acc[nt][t4]);           \
      }                                                           \
    }                                                             \
  }

  STAGE_X(0);
  STAGE_X(1);
  ITER(0, "16");
  ITER(1, "16");
  ITER(2, "16");
  ITER(3, "16");
  ITER(4, "16");
  ITER(5, "16");
  ITER(6, "8");
  ITER(7, "0");

  // epilogue: D col=token(le), row=expert=nt*16+4*lg+j. LOGIT-domain select.
#pragma unroll
  for (int tt = 0; tt < 4; ++tt) {
    float l[16];
#pragma unroll
    for (int nt = 0; nt < 4; ++nt)
#pragma unroll
      for (int j = 0; j < 4; ++j) l[nt * 4 + j] = acc[nt][tt][j];

    float g0 = l[0], g1 = l[8];
#pragma unroll
    for (int j = 1; j < 8; ++j) {
      g0 = fmaxf(g0, l[j]);
      g1 = fmaxf(g1, l[8 + j]);
    }
    g0 = fmaxf(g0, __shfl_xor(g0, 16));
    g0 = fmaxf(g0, __shfl_xor(g0, 32));
    g1 = fmaxf(g1, __shfl_xor(g1, 16));
    g1 = fmaxf(g1, __shfl_xor(g1, 32));
    const int g = (g1 > g0) ? 1 : 0;  // tie -> group 0
    const float m = fmaxf(g0, g1);

    float sum = 0.f;
#pragma unroll
    for (int k = 0; k < 16; ++k) sum += __expf(l[k] - m);
    sum += __shfl_xor(sum, 16);
    sum += __shfl_xor(sum, 32);
    const float inv = 1.0f / sum;

    float c[8];
    int ce[8];
#pragma unroll
    for (int j2 = 0; j2 < 8; ++j2) {
      c[j2] = l[g * 8 + j2];
      ce[j2] = (2 * g + (j2 >> 2)) * 16 + 4 * lg + (j2 & 3);
    }

    float v5[5];
    int e5[5];
#pragma unroll
    for (int it = 0; it < 5; ++it) {
      float bv = c[0];
      int be = ce[0];
#pragma unroll
      for (int j2 = 1; j2 < 8; ++j2) {  // strict > keeps lowest index
        bool gt = c[j2] > bv;
        bv = gt ? c[j2] : bv;
        be = gt ? ce[j2] : be;
      }
#pragma unroll
      for (int st = 0; st < 2; ++st) {
        int msk = 16 << st;
        float ov = __shfl_xor(bv, msk);
        int oe = __shfl_xor(be, msk);
        bool tk = (ov > bv) || (ov == bv && oe < be);
        bv = tk ? ov : bv;
        be = tk ? oe : be;
      }
      v5[it] = bv;
      e5[it] = be;
#pragma unroll
      for (int j2 = 0; j2 < 8; ++j2)
        c[j2] = (ce[j2] == be) ? -3.0e38f : c[j2];
    }

    float ming = fabsf(g0 - g1);
#pragma unroll
    for (int it = 0; it < 4; ++it) ming = fminf(ming, v5[it] - v5[it + 1]);

    if (lg == 0) {
      size_t trow = (size_t)tokbase + tt * 16 + le;
      *(float4*)&out[trow * 4] =
          make_float4(__expf(v5[0] - m) * inv, __expf(v5[1] - m) * inv,
                      __expf(v5[2] - m) * inv, __expf(v5[3] - m) * inv);
      *(float4*)&out[(size_t)T * 4 + trow * 4] = make_float4(
          (float)e5[0], (float)e5[1], (float)e5[2], (float)e5[3]);
      if (ming < DELTA) {
        int p = atomicAdd(meta, 1);
        if (p < cap) list[p] = (int)trow;
      }
    }
  }
}

// exact recompute of flagged tokens: one wave per token, lane = expert.
__global__ __launch_bounds__(64) void fix_kernel(
    const float* __restrict__ x, const float* __restrict__ W,
    float* __restrict__ out, const int* __restrict__ meta,
    const int* __restrict__ list, int cap, int T) {
  const int e = threadIdx.x;
  int cnt = meta[0];
  cnt = cnt < cap ? cnt : cap;
  for (int i = blockIdx.x; i < cnt; i += gridDim.x) {
    const int tok = list[i];
    const float* xr = x + (size_t)tok * 256;
    const float* wr = W + (size_t)e * 256;
    float acc = 0.f;
#pragma unroll 8
    for (int d = 0; d < 256; d += 4) {  // single-acc ascending-d fmaf chain
      float4 xv = *(const float4*)(xr + d);
      float4 wv = *(const float4*)(wr + d);
      acc = fmaf(xv.x, wv.x, acc);
      acc = fmaf(xv.y, wv.y, acc);
      acc = fmaf(xv.z, wv.z, acc);
      acc = fmaf(xv.w, wv.w, acc);
    }
    float gm = acc;
#pragma unroll
    for (int st = 0; st < 5; ++st) gm = fmaxf(gm, __shfl_xor(gm, 1 << st));
    float om = __shfl_xor(gm, 32);
    float g0 = (e < 32) ? gm : om;
    float g1 = (e < 32) ? om : gm;
    const int g = (g1 > g0) ? 1 : 0;
    const float m = fmaxf(g0, g1);
    float sum = __expf(acc - m);
#pragma unroll
    for (int st = 0; st < 6; ++st) sum += __shfl_xor(sum, 1 << st);
    const float inv = 1.0f / sum;

    float cand = ((e >> 5) == g) ? acc : -3.0e38f;
    float w4[4], i4[4];
#pragma unroll
    for (int it = 0; it < 4; ++it) {
      float bv = cand;
      int be = e;
#pragma unroll
      for (int st = 0; st < 6; ++st) {
        int msk = 1 << st;
        float ov = __shfl_xor(bv, msk);
        int oe = __shfl_xor(be, msk);
        bool tk = (ov > bv) || (ov == bv && oe < be);
        bv = tk ? ov : bv;
        be = tk ? oe : be;
      }
      w4[it] = __expf(bv - m) * inv;
      i4[it] = (float)be;
      if (e == be) cand = -3.0e38f;
    }
    if (e == 0) {
      *(float4*)&out[(size_t)tok * 4] = make_float4(w4[0], w4[1], w4[2], w4[3]);
      *(float4*)&out[(size_t)T * 4 + (size_t)tok * 4] =
          make_float4(i4[0], i4[1], i4[2], i4[3]);
    }
  }
}

extern "C" void kernel_launch(void* const* d_in, const int* in_sizes, int n_in,
                              void* d_out, int out_size, void* d_ws,
                              size_t ws_size, hipStream_t stream) {
  const float* x = (const float*)d_in[0];
  const float* W = (const float*)d_in[1];
  float* out = (float*)d_out;
  int T = in_sizes[0] / 256;  // D = 256
  int nW = in_sizes[1];       // 16384
  int* meta = (int*)d_ws;
  unsigned short* wsp = (unsigned short*)((char*)d_ws + SPLIT_OFF);
  int* list = (int*)((char*)d_ws + LIST_OFF);
  int cap = (ws_size > LIST_OFF + 4) ? (int)((ws_size - LIST_OFF) / 4) : 0;
  hipLaunchKernelGGL(zero_meta, dim3(1), dim3(1), 0, stream, meta);
  hipLaunchKernelGGL(split_w, dim3((nW + 255) / 256), dim3(256), 0, stream, W,
                     wsp, nW);
  hipLaunchKernelGGL(gate_kernel, dim3(T / 256), dim3(256), 0, stream, x, wsp,
                     out, meta, list, cap, T);
  hipLaunchKernelGGL(fix_kernel, dim3(2048), dim3(64), 0, stream, x, W, out,
                     meta, list, cap, T);
}

// Round 8
// 145.742 us; speedup vs baseline: 15.7908x; 1.0163x over previous
//
#include <hip/hip_runtime.h>
#include <hip/hip_bf16.h>
#include <stdint.h>

// MoE gate: T=524288, D=256, E=64, groups=2x32, topk=4.
// Pass 1: logits^T = W @ x^T via mfma_f32_16x16x32_bf16. W and x each split
//   into 2 bf16 truncation levels; 4 cross terms (hh,hm,mh,mm); dropped-term
//   sigma ~7e-6 << DELTA=1e-4. W-split staged once per block into LDS
//   (global_load_lds overlapped with x prefetch, counted vmcnt + raw
//   s_barrier -- no drain). x flows global->reg (inline asm, DEPTH-3
//   prefetch, counted s_waitcnt vmcnt, never 0 in steady state).
// Pass 2: tokens with selection margin < DELTA recomputed exactly (np-order
//   fmaf chain) by fix_kernel (~1% of tokens).

typedef __attribute__((ext_vector_type(8))) short bf16x8;
typedef __attribute__((ext_vector_type(4))) float f32x4;
typedef __attribute__((ext_vector_type(4))) int i32x4;

#define SPLIT_OFF 1024
#define LIST_OFF 102400
#define DELTA 1e-4f

__device__ __forceinline__ f32x4 mf(const i32x4& a, const i32x4& b,
                                    const f32x4& c) {
  return __builtin_amdgcn_mfma_f32_16x16x32_bf16(
      __builtin_bit_cast(bf16x8, a), __builtin_bit_cast(bf16x8, b), c, 0, 0, 0);
}

// low short = hi16(e0), high short = hi16(e1)
__device__ __forceinline__ int packhi(unsigned e0, unsigned e1) {
  return (int)__builtin_amdgcn_perm(e1, e0, 0x07060302u);
}

__device__ __forceinline__ void gload16(const void* g, void* l) {
  __builtin_amdgcn_global_load_lds(
      (const __attribute__((address_space(1))) void*)g,
      (__attribute__((address_space(3))) void*)l, 16, 0, 0);
}

__global__ void zero_meta(int* meta) { meta[0] = 0; }

// W -> 2 bf16 truncation levels (h, m), packed in MFMA A-fragment
// chunk-major layout: frag(c, q=v*4+nt) is 1KB; lane(=lg*16+le)*16B holds
// W_v[e=nt*16+le][k=c*32+lg*8 .. +8].
__global__ void split_w(const float* __restrict__ W,
                        unsigned short* __restrict__ ws, int n) {
  int i = blockIdx.x * 256 + threadIdx.x;
  if (i >= n) return;
  float w = W[i];
  unsigned u = __float_as_uint(w);
  unsigned uh = u & 0xFFFF0000u;
  float rf = w - __uint_as_float(uh);  // exact
  unsigned short lv[2];
  lv[0] = (unsigned short)(uh >> 16);
  lv[1] = (unsigned short)(__float_as_uint(rf) >> 16);
  int e = i >> 8, k = i & 255;
  int nt = e >> 4, le = e & 15;
  int c = k >> 5, lg = (k >> 3) & 3, kk = k & 7;
  int lane = lg * 16 + le;
#pragma unroll
  for (int v = 0; v < 2; ++v)
    ws[(((c * 8 + v * 4 + nt) * 64) + lane) * 8 + kk] = lv[v];
}

struct XF2 { i32x4 h, m; };

__device__ __forceinline__ XF2 split2(f32x4 a, f32x4 b) {
  float xs[8] = {a[0], a[1], a[2], a[3], b[0], b[1], b[2], b[3]};
  XF2 f;
#pragma unroll
  for (int wd = 0; wd < 4; ++wd) {
    unsigned u0 = __float_as_uint(xs[2 * wd]);
    unsigned u1 = __float_as_uint(xs[2 * wd + 1]);
    f.h[wd] = packhi(u0, u1);
    float r0 = xs[2 * wd] - __uint_as_float(u0 & 0xFFFF0000u);      // exact
    float r1 = xs[2 * wd + 1] - __uint_as_float(u1 & 0xFFFF0000u);  // exact
    f.m[wd] = packhi(__float_as_uint(r0), __float_as_uint(r1));
  }
  return f;
}

// inline-asm global load with immediate offset; valid after matching WAITV.
#define GL(dst, ptr, OFF)                                     \
  asm volatile("global_load_dwordx4 %0, %1, off offset:%2"    \
               : "=v"(dst)                                    \
               : "v"(ptr), "n"(OFF))

#define WAITV(NSTR)                                         \
  do {                                                      \
    asm volatile("s_waitcnt vmcnt(" NSTR ")" ::: "memory"); \
    __builtin_amdgcn_sched_barrier(0);                      \
  } while (0)

__global__ __launch_bounds__(256, 2) void gate_kernel(
    const float* __restrict__ x, const unsigned short* __restrict__ wsp,
    float* __restrict__ out, int* __restrict__ meta, int* __restrict__ list,
    int cap, int T) {
  __shared__ i32x4 WL[4096];  // 64 KB: W-split fragments, chunk-major

  const int t = threadIdx.x;
  const int lane = t & 63;
  const int wid = t >> 6;
  const int le = lane & 15;  // token col / expert row within 16-tile
  const int lg = lane >> 4;  // k-quad group
  const int tokbase = blockIdx.x * 256 + wid * 64;

  const float* xa0 = x + (size_t)(tokbase + le) * 256 + lg * 8;
  const float* xa1 = xa0 + 16 * 256;
  const float* xa2 = xa0 + 32 * 256;
  const float* xa3 = xa0 + 48 * 256;

  f32x4 xbuf[4][8];  // depth-3 x prefetch, static rotation
  f32x4 acc[4][4];   // [nt][tile]
#pragma unroll
  for (int nt = 0; nt < 4; ++nt)
#pragma unroll
    for (int t4 = 0; t4 < 4; ++t4) acc[nt][t4] = (f32x4)0.0f;

#define STAGE_X(c)                              \
  do {                                          \
    GL(xbuf[(c) & 3][0], xa0, (c) * 128);       \
    GL(xbuf[(c) & 3][1], xa0, (c) * 128 + 16);  \
    GL(xbuf[(c) & 3][2], xa1, (c) * 128);       \
    GL(xbuf[(c) & 3][3], xa1, (c) * 128 + 16);  \
    GL(xbuf[(c) & 3][4], xa2, (c) * 128);       \
    GL(xbuf[(c) & 3][5], xa2, (c) * 128 + 16);  \
    GL(xbuf[(c) & 3][6], xa3, (c) * 128);       \
    GL(xbuf[(c) & 3][7], xa3, (c) * 128 + 16);  \
  } while (0)

#define ITER(c, NSTR)                                                   \
  {                                                                     \
    if ((c) + 3 < 8) STAGE_X((c) + 3);                                  \
    i32x4 wr[8];                                                        \
    _Pragma("unroll") for (int q = 0; q < 8; ++q)                       \
        wr[q] = WL[(((c) * 8 + q) << 6) + lane];                        \
    WAITV(NSTR);                                                        \
    _Pragma("unroll") for (int t4 = 0; t4 < 4; ++t4) {                  \
      XF2 b = split2(xbuf[(c) & 3][2 * t4], xbuf[(c) & 3][2 * t4 + 1]); \
      _Pragma("unroll") for (int nt = 0; nt < 4; ++nt) {                \
        acc[nt][t4] = mf(wr[nt], b.h, acc[nt][t4]);                     \
        acc[nt][t4] = mf(wr[nt], b.m, acc[nt][t4]);                     \
        acc[nt][t4] = mf(wr[4 + nt], b.h, acc[nt][t4]);                 \
        acc[nt][t4] = mf(wr[4 + nt], b.m, acc[nt][t4]);                 \
      }                                                                 \
    }                                                                   \
  }

  // ---- prologue: W gload_lds first, then x chunks 0..2; counted wait
  // completes exactly the W loads (x stays in flight); raw barrier. ----
  {
    const char* wsrc = (const char*)wsp + t * 16;
    char* wdst = (char*)WL + t * 16;
#pragma unroll
    for (int i = 0; i < 16; ++i) gload16(wsrc + i * 4096, wdst + i * 4096);
  }
  STAGE_X(0);
  STAGE_X(1);
  STAGE_X(2);
  WAITV("24");
  __builtin_amdgcn_s_barrier();

  ITER(0, "24");
  ITER(1, "24");
  ITER(2, "24");
  ITER(3, "24");
  ITER(4, "24");
  ITER(5, "16");
  ITER(6, "8");
  ITER(7, "0");

  // epilogue: D col=token(le), row=expert=nt*16+4*lg+j. LOGIT-domain select.
#pragma unroll
  for (int tt = 0; tt < 4; ++tt) {
    float l[16];
#pragma unroll
    for (int nt = 0; nt < 4; ++nt)
#pragma unroll
      for (int j = 0; j < 4; ++j) l[nt * 4 + j] = acc[nt][tt][j];

    float g0 = l[0], g1 = l[8];
#pragma unroll
    for (int j = 1; j < 8; ++j) {
      g0 = fmaxf(g0, l[j]);
      g1 = fmaxf(g1, l[8 + j]);
    }
    g0 = fmaxf(g0, __shfl_xor(g0, 16));
    g0 = fmaxf(g0, __shfl_xor(g0, 32));
    g1 = fmaxf(g1, __shfl_xor(g1, 16));
    g1 = fmaxf(g1, __shfl_xor(g1, 32));
    const int g = (g1 > g0) ? 1 : 0;  // tie -> group 0
    const float m = fmaxf(g0, g1);

    float sum = 0.f;
#pragma unroll
    for (int k = 0; k < 16; ++k) sum += __expf(l[k] - m);
    sum += __shfl_xor(sum, 16);
    sum += __shfl_xor(sum, 32);
    const float inv = 1.0f / sum;

    float c[8];
    int ce[8];
#pragma unroll
    for (int j2 = 0; j2 < 8; ++j2) {
      c[j2] = l[g * 8 + j2];
      ce[j2] = (2 * g + (j2 >> 2)) * 16 + 4 * lg + (j2 & 3);
    }

    float v5[5];
    int e5[5];
#pragma unroll
    for (int it = 0; it < 5; ++it) {
      float bv = c[0];
      int be = ce[0];
#pragma unroll
      for (int j2 = 1; j2 < 8; ++j2) {  // strict > keeps lowest index
        bool gt = c[j2] > bv;
        bv = gt ? c[j2] : bv;
        be = gt ? ce[j2] : be;
      }
#pragma unroll
      for (int st = 0; st < 2; ++st) {
        int msk = 16 << st;
        float ov = __shfl_xor(bv, msk);
        int oe = __shfl_xor(be, msk);
        bool tk = (ov > bv) || (ov == bv && oe < be);
        bv = tk ? ov : bv;
        be = tk ? oe : be;
      }
      v5[it] = bv;
      e5[it] = be;
#pragma unroll
      for (int j2 = 0; j2 < 8; ++j2)
        c[j2] = (ce[j2] == be) ? -3.0e38f : c[j2];
    }

    float ming = fabsf(g0 - g1);
#pragma unroll
    for (int it = 0; it < 4; ++it) ming = fminf(ming, v5[it] - v5[it + 1]);

    if (lg == 0) {
      size_t trow = (size_t)tokbase + tt * 16 + le;
      *(float4*)&out[trow * 4] =
          make_float4(__expf(v5[0] - m) * inv, __expf(v5[1] - m) * inv,
                      __expf(v5[2] - m) * inv, __expf(v5[3] - m) * inv);
      *(float4*)&out[(size_t)T * 4 + trow * 4] = make_float4(
          (float)e5[0], (float)e5[1], (float)e5[2], (float)e5[3]);
      if (ming < DELTA) {
        int p = atomicAdd(meta, 1);
        if (p < cap) list[p] = (int)trow;
      }
    }
  }
}

// exact recompute of flagged tokens: one wave per token, lane = expert.
__global__ __launch_bounds__(64) void fix_kernel(
    const float* __restrict__ x, const float* __restrict__ W,
    float* __restrict__ out, const int* __restrict__ meta,
    const int* __restrict__ list, int cap, int T) {
  const int e = threadIdx.x;
  int cnt = meta[0];
  cnt = cnt < cap ? cnt : cap;
  for (int i = blockIdx.x; i < cnt; i += gridDim.x) {
    const int tok = list[i];
    const float* xr = x + (size_t)tok * 256;
    const float* wr = W + (size_t)e * 256;
    float acc = 0.f;
#pragma unroll 8
    for (int d = 0; d < 256; d += 4) {  // single-acc ascending-d fmaf chain
      float4 xv = *(const float4*)(xr + d);
      float4 wv = *(const float4*)(wr + d);
      acc = fmaf(xv.x, wv.x, acc);
      acc = fmaf(xv.y, wv.y, acc);
      acc = fmaf(xv.z, wv.z, acc);
      acc = fmaf(xv.w, wv.w, acc);
    }
    float gm = acc;
#pragma unroll
    for (int st = 0; st < 5; ++st) gm = fmaxf(gm, __shfl_xor(gm, 1 << st));
    float om = __shfl_xor(gm, 32);
    float g0 = (e < 32) ? gm : om;
    float g1 = (e < 32) ? om : gm;
    const int g = (g1 > g0) ? 1 : 0;
    const float m = fmaxf(g0, g1);
    float sum = __expf(acc - m);
#pragma unroll
    for (int st = 0; st < 6; ++st) sum += __shfl_xor(sum, 1 << st);
    const float inv = 1.0f / sum;

    float cand = ((e >> 5) == g) ? acc : -3.0e38f;
    float w4[4], i4[4];
#pragma unroll
    for (int it = 0; it < 4; ++it) {
      float bv = cand;
      int be = e;
#pragma unroll
      for (int st = 0; st < 6; ++st) {
        int msk = 1 << st;
        float ov = __shfl_xor(bv, msk);
        int oe = __shfl_xor(be, msk);
        bool tk = (ov > bv) || (ov == bv && oe < be);
        bv = tk ? ov : bv;
        be = tk ? oe : be;
      }
      w4[it] = __expf(bv - m) * inv;
      i4[it] = (float)be;
      if (e == be) cand = -3.0e38f;
    }
    if (e == 0) {
      *(float4*)&out[(size_t)tok * 4] = make_float4(w4[0], w4[1], w4[2], w4[3]);
      *(float4*)&out[(size_t)T * 4 + (size_t)tok * 4] =
          make_float4(i4[0], i4[1], i4[2], i4[3]);
    }
  }
}

extern "C" void kernel_launch(void* const* d_in, const int* in_sizes, int n_in,
                              void* d_out, int out_size, void* d_ws,
                              size_t ws_size, hipStream_t stream) {
  const float* x = (const float*)d_in[0];
  const float* W = (const float*)d_in[1];
  float* out = (float*)d_out;
  int T = in_sizes[0] / 256;  // D = 256
  int nW = in_sizes[1];       // 16384
  int* meta = (int*)d_ws;
  unsigned short* wsp = (unsigned short*)((char*)d_ws + SPLIT_OFF);
  int* list = (int*)((char*)d_ws + LIST_OFF);
  int cap = (ws_size > LIST_OFF + 4) ? (int)((ws_size - LIST_OFF) / 4) : 0;
  hipLaunchKernelGGL(zero_meta, dim3(1), dim3(1), 0, stream, meta);
  hipLaunchKernelGGL(split_w, dim3((nW + 255) / 256), dim3(256), 0, stream, W,
                     wsp, nW);
  hipLaunchKernelGGL(gate_kernel, dim3(T / 256), dim3(256), 0, stream, x, wsp,
                     out, meta, list, cap, T);
  hipLaunchKernelGGL(fix_kernel, dim3(2048), dim3(64), 0, stream, x, W, out,
                     meta, list, cap, T);
}

// Round 9
// 142.147 us; speedup vs baseline: 16.1902x; 1.0253x over previous
//
#include <hip/hip_runtime.h>
#include <hip/hip_bf16.h>
#include <stdint.h>

// MoE gate: T=524288, D=256, E=64, groups=2x32, topk=4.
// Pass 1: logits^T = W @ x^T via mfma_f32_16x16x32_bf16. W and x each split
//   into 2 bf16 truncation levels; 4 cross terms; dropped-term sigma ~1e-6
//   << DELTA=1e-4. W-split staged once per block into LDS (overlapped with
//   x prefetch, counted vmcnt + raw s_barrier -- no drain). x global->reg,
//   depth-2 prefetch with 2 buffers (mid-ITER re-issue), counted vmcnt.
//   512-thread blocks, 32 tokens/wave, VGPR<=128 -> 4 waves/SIMD.
// Pass 2: tokens with selection margin < DELTA recomputed exactly (np-order
//   fmaf chain) by fix_kernel (~1% of tokens).

typedef __attribute__((ext_vector_type(8))) short bf16x8;
typedef __attribute__((ext_vector_type(4))) float f32x4;
typedef __attribute__((ext_vector_type(4))) int i32x4;

#define SPLIT_OFF 1024
#define LIST_OFF 102400
#define DELTA 1e-4f

__device__ __forceinline__ f32x4 mf(const i32x4& a, const i32x4& b,
                                    const f32x4& c) {
  return __builtin_amdgcn_mfma_f32_16x16x32_bf16(
      __builtin_bit_cast(bf16x8, a), __builtin_bit_cast(bf16x8, b), c, 0, 0, 0);
}

// low short = hi16(e0), high short = hi16(e1)
__device__ __forceinline__ int packhi(unsigned e0, unsigned e1) {
  return (int)__builtin_amdgcn_perm(e1, e0, 0x07060302u);
}

__device__ __forceinline__ void gload16(const void* g, void* l) {
  __builtin_amdgcn_global_load_lds(
      (const __attribute__((address_space(1))) void*)g,
      (__attribute__((address_space(3))) void*)l, 16, 0, 0);
}

// W -> 2 bf16 truncation levels (h, m), packed in MFMA A-fragment
// chunk-major layout: frag(c, q=v*4+nt) is 1KB; lane(=lg*16+le)*16B holds
// W_v[e=nt*16+le][k=c*32+lg*8 .. +8]. Also zeroes the fix-list counter.
__global__ void split_w(const float* __restrict__ W,
                        unsigned short* __restrict__ ws, int n,
                        int* __restrict__ meta) {
  int i = blockIdx.x * 256 + threadIdx.x;
  if (i == 0) meta[0] = 0;
  if (i >= n) return;
  float w = W[i];
  unsigned u = __float_as_uint(w);
  unsigned uh = u & 0xFFFF0000u;
  float rf = w - __uint_as_float(uh);  // exact
  unsigned short lv[2];
  lv[0] = (unsigned short)(uh >> 16);
  lv[1] = (unsigned short)(__float_as_uint(rf) >> 16);
  int e = i >> 8, k = i & 255;
  int nt = e >> 4, le = e & 15;
  int c = k >> 5, lg = (k >> 3) & 3, kk = k & 7;
  int lane = lg * 16 + le;
#pragma unroll
  for (int v = 0; v < 2; ++v)
    ws[(((c * 8 + v * 4 + nt) * 64) + lane) * 8 + kk] = lv[v];
}

struct XF2 { i32x4 h, m; };

__device__ __forceinline__ XF2 split2(f32x4 a, f32x4 b) {
  float xs[8] = {a[0], a[1], a[2], a[3], b[0], b[1], b[2], b[3]};
  XF2 f;
#pragma unroll
  for (int wd = 0; wd < 4; ++wd) {
    unsigned u0 = __float_as_uint(xs[2 * wd]);
    unsigned u1 = __float_as_uint(xs[2 * wd + 1]);
    f.h[wd] = packhi(u0, u1);
    float r0 = xs[2 * wd] - __uint_as_float(u0 & 0xFFFF0000u);      // exact
    float r1 = xs[2 * wd + 1] - __uint_as_float(u1 & 0xFFFF0000u);  // exact
    f.m[wd] = packhi(__float_as_uint(r0), __float_as_uint(r1));
  }
  return f;
}

// inline-asm global load with immediate offset; valid after matching WAITV.
#define GL(dst, ptr, OFF)                                     \
  asm volatile("global_load_dwordx4 %0, %1, off offset:%2"    \
               : "=v"(dst)                                    \
               : "v"(ptr), "n"(OFF))

#define WAITV(NSTR)                                         \
  do {                                                      \
    asm volatile("s_waitcnt vmcnt(" NSTR ")" ::: "memory"); \
    __builtin_amdgcn_sched_barrier(0);                      \
  } while (0)

__global__ __launch_bounds__(512, 4) void gate_kernel(
    const float* __restrict__ x, const unsigned short* __restrict__ wsp,
    float* __restrict__ out, int* __restrict__ meta, int* __restrict__ list,
    int cap, int T) {
  __shared__ i32x4 WL[4096];  // 64 KB: W-split fragments, chunk-major

  const int t = threadIdx.x;
  const int lane = t & 63;
  const int wid = t >> 6;    // 0..7
  const int le = lane & 15;  // token col / expert row within 16-tile
  const int lg = lane >> 4;  // k-quad group
  const int tokbase = blockIdx.x * 256 + wid * 32;

  const float* xa0 = x + (size_t)(tokbase + le) * 256 + lg * 8;
  const float* xa1 = xa0 + 16 * 256;

  f32x4 xbuf[2][4];  // depth-2, 2 buffers (freed buffer re-issued mid-ITER)
  f32x4 acc[4][2];   // [nt][tile]
#pragma unroll
  for (int nt = 0; nt < 4; ++nt)
#pragma unroll
    for (int t2 = 0; t2 < 2; ++t2) acc[nt][t2] = (f32x4)0.0f;

#define STAGE_X(c)                              \
  do {                                          \
    GL(xbuf[(c) & 1][0], xa0, (c) * 128);       \
    GL(xbuf[(c) & 1][1], xa0, (c) * 128 + 16);  \
    GL(xbuf[(c) & 1][2], xa1, (c) * 128);       \
    GL(xbuf[(c) & 1][3], xa1, (c) * 128 + 16);  \
  } while (0)

  // ITER c: wait x(c); split to bf16 frags (frees xbuf[c&1]); re-issue
  // x(c+2) into the freed buffer (WAR safe: reads precede the GL in issue
  // order); then W ds_reads + 32 MFMAs. No per-ITER barriers.
#define ITER(c, NSTR)                                               \
  {                                                                 \
    WAITV(NSTR);                                                    \
    XF2 b0 = split2(xbuf[(c) & 1][0], xbuf[(c) & 1][1]);            \
    XF2 b1 = split2(xbuf[(c) & 1][2], xbuf[(c) & 1][3]);            \
    if ((c) + 2 < 8) STAGE_X((c) + 2);                              \
    _Pragma("unroll") for (int nt = 0; nt < 4; ++nt) {              \
      i32x4 ah = WL[(((c) * 8 + nt) << 6) + lane];                  \
      i32x4 am = WL[(((c) * 8 + 4 + nt) << 6) + lane];              \
      acc[nt][0] = mf(ah, b0.h, acc[nt][0]);                        \
      acc[nt][0] = mf(ah, b0.m, acc[nt][0]);                        \
      acc[nt][0] = mf(am, b0.h, acc[nt][0]);                        \
      acc[nt][0] = mf(am, b0.m, acc[nt][0]);                        \
      acc[nt][1] = mf(ah, b1.h, acc[nt][1]);                        \
      acc[nt][1] = mf(ah, b1.m, acc[nt][1]);                        \
      acc[nt][1] = mf(am, b1.h, acc[nt][1]);                        \
      acc[nt][1] = mf(am, b1.m, acc[nt][1]);                        \
    }                                                               \
  }

  // ---- prologue: W gload_lds (8/thread, 64KB/block), then x chunks 0,1;
  // counted wait completes exactly W (x stays in flight); raw barrier. ----
  {
    const char* wsrc = (const char*)wsp + t * 16;
    char* wdst = (char*)WL + t * 16;
#pragma unroll
    for (int i = 0; i < 8; ++i) gload16(wsrc + i * 8192, wdst + i * 8192);
  }
  STAGE_X(0);
  STAGE_X(1);
  WAITV("8");
  __builtin_amdgcn_s_barrier();

  ITER(0, "4");
  ITER(1, "4");
  ITER(2, "4");
  ITER(3, "4");
  ITER(4, "4");
  ITER(5, "4");
  ITER(6, "4");
  ITER(7, "0");

  // epilogue: D col=token(le), row=expert=nt*16+4*lg+j. LOGIT-domain select.
#pragma unroll
  for (int tt = 0; tt < 2; ++tt) {
    float l[16];
#pragma unroll
    for (int nt = 0; nt < 4; ++nt)
#pragma unroll
      for (int j = 0; j < 4; ++j) l[nt * 4 + j] = acc[nt][tt][j];

    float g0 = l[0], g1 = l[8];
#pragma unroll
    for (int j = 1; j < 8; ++j) {
      g0 = fmaxf(g0, l[j]);
      g1 = fmaxf(g1, l[8 + j]);
    }
    g0 = fmaxf(g0, __shfl_xor(g0, 16));
    g0 = fmaxf(g0, __shfl_xor(g0, 32));
    g1 = fmaxf(g1, __shfl_xor(g1, 16));
    g1 = fmaxf(g1, __shfl_xor(g1, 32));
    const int g = (g1 > g0) ? 1 : 0;  // tie -> group 0
    const float m = fmaxf(g0, g1);

    float sum = 0.f;
#pragma unroll
    for (int k = 0; k < 16; ++k) sum += __expf(l[k] - m);
    sum += __shfl_xor(sum, 16);
    sum += __shfl_xor(sum, 32);
    const float inv = 1.0f / sum;

    float c[8];
    int ce[8];
#pragma unroll
    for (int j2 = 0; j2 < 8; ++j2) {
      c[j2] = l[g * 8 + j2];
      ce[j2] = (2 * g + (j2 >> 2)) * 16 + 4 * lg + (j2 & 3);
    }

    float v5[5];
    int e5[5];
#pragma unroll
    for (int it = 0; it < 5; ++it) {
      float bv = c[0];
      int be = ce[0];
#pragma unroll
      for (int j2 = 1; j2 < 8; ++j2) {  // strict > keeps lowest index
        bool gt = c[j2] > bv;
        bv = gt ? c[j2] : bv;
        be = gt ? ce[j2] : be;
      }
#pragma unroll
      for (int st = 0; st < 2; ++st) {
        int msk = 16 << st;
        float ov = __shfl_xor(bv, msk);
        int oe = __shfl_xor(be, msk);
        bool tk = (ov > bv) || (ov == bv && oe < be);
        bv = tk ? ov : bv;
        be = tk ? oe : be;
      }
      v5[it] = bv;
      e5[it] = be;
#pragma unroll
      for (int j2 = 0; j2 < 8; ++j2)
        c[j2] = (ce[j2] == be) ? -3.0e38f : c[j2];
    }

    float ming = fabsf(g0 - g1);
#pragma unroll
    for (int it = 0; it < 4; ++it) ming = fminf(ming, v5[it] - v5[it + 1]);

    if (lg == 0) {
      size_t trow = (size_t)tokbase + tt * 16 + le;
      *(float4*)&out[trow * 4] =
          make_float4(__expf(v5[0] - m) * inv, __expf(v5[1] - m) * inv,
                      __expf(v5[2] - m) * inv, __expf(v5[3] - m) * inv);
      *(float4*)&out[(size_t)T * 4 + trow * 4] = make_float4(
          (float)e5[0], (float)e5[1], (float)e5[2], (float)e5[3]);
      if (ming < DELTA) {
        int p = atomicAdd(meta, 1);
        if (p < cap) list[p] = (int)trow;
      }
    }
  }
}

// exact recompute of flagged tokens: one wave per token, lane = expert.
__global__ __launch_bounds__(64) void fix_kernel(
    const float* __restrict__ x, const float* __restrict__ W,
    float* __restrict__ out, const int* __restrict__ meta,
    const int* __restrict__ list, int cap, int T) {
  const int e = threadIdx.x;
  int cnt = meta[0];
  cnt = cnt < cap ? cnt : cap;
  for (int i = blockIdx.x; i < cnt; i += gridDim.x) {
    const int tok = list[i];
    const float* xr = x + (size_t)tok * 256;
    const float* wr = W + (size_t)e * 256;
    float acc = 0.f;
#pragma unroll 8
    for (int d = 0; d < 256; d += 4) {  // single-acc ascending-d fmaf chain
      float4 xv = *(const float4*)(xr + d);
      float4 wv = *(const float4*)(wr + d);
      acc = fmaf(xv.x, wv.x, acc);
      acc = fmaf(xv.y, wv.y, acc);
      acc = fmaf(xv.z, wv.z, acc);
      acc = fmaf(xv.w, wv.w, acc);
    }
    float gm = acc;
#pragma unroll
    for (int st = 0; st < 5; ++st) gm = fmaxf(gm, __shfl_xor(gm, 1 << st));
    float om = __shfl_xor(gm, 32);
    float g0 = (e < 32) ? gm : om;
    float g1 = (e < 32) ? om : gm;
    const int g = (g1 > g0) ? 1 : 0;
    const float m = fmaxf(g0, g1);
    float sum = __expf(acc - m);
#pragma unroll
    for (int st = 0; st < 6; ++st) sum += __shfl_xor(sum, 1 << st);
    const float inv = 1.0f / sum;

    float cand = ((e >> 5) == g) ? acc : -3.0e38f;
    float w4[4], i4[4];
#pragma unroll
    for (int it = 0; it < 4; ++it) {
      float bv = cand;
      int be = e;
#pragma unroll
      for (int st = 0; st < 6; ++st) {
        int msk = 1 << st;
        float ov = __shfl_xor(bv, msk);
        int oe = __shfl_xor(be, msk);
        bool tk = (ov > bv) || (ov == bv && oe < be);
        bv = tk ? ov : bv;
        be = tk ? oe : be;
      }
      w4[it] = __expf(bv - m) * inv;
      i4[it] = (float)be;
      if (e == be) cand = -3.0e38f;
    }
    if (e == 0) {
      *(float4*)&out[(size_t)tok * 4] = make_float4(w4[0], w4[1], w4[2], w4[3]);
      *(float4*)&out[(size_t)T * 4 + (size_t)tok * 4] =
          make_float4(i4[0], i4[1], i4[2], i4[3]);
    }
  }
}

extern "C" void kernel_launch(void* const* d_in, const int* in_sizes, int n_in,
                              void* d_out, int out_size, void* d_ws,
                              size_t ws_size, hipStream_t stream) {
  const float* x = (const float*)d_in[0];
  const float* W = (const float*)d_in[1];
  float* out = (float*)d_out;
  int T = in_sizes[0] / 256;  // D = 256
  int nW = in_sizes[1];       // 16384
  int* meta = (int*)d_ws;
  unsigned short* wsp = (unsigned short*)((char*)d_ws + SPLIT_OFF);
  int* list = (int*)((char*)d_ws + LIST_OFF);
  int cap = (ws_size > LIST_OFF + 4) ? (int)((ws_size - LIST_OFF) / 4) : 0;
  hipLaunchKernelGGL(split_w, dim3((nW + 255) / 256), dim3(256), 0, stream, W,
                     wsp, nW, meta);
  hipLaunchKernelGGL(gate_kernel, dim3(T / 256), dim3(512), 0, stream, x, wsp,
                     out, meta, list, cap, T);
  hipLaunchKernelGGL(fix_kernel, dim3(2048), dim3(64), 0, stream, x, W, out,
                     meta, list, cap, T);
}